// Round 11
// baseline (203.682 us; speedup 1.0000x reference)
//
#include <hip/hip_runtime.h>
#include <hip/hip_fp16.h>

#define N_NODES 50000
#define N_EDGES 800000
#define NEG_SLOPE 0.2f
#define NBKT 196            // ceil(50000/256) buckets of 256 nodes
#define EBLK 200            // edge blocks
#define CHUNK 4000          // edges per block (EBLK*CHUNK == N_EDGES)
#define GEMM_BLOCKS 782     // ceil(50000/64)

__device__ __forceinline__ float leaky(float x) { return x >= 0.f ? x : NEG_SLOPE * x; }
__device__ __forceinline__ float readlane_f(float v, int i) {
    return __uint_as_float(__builtin_amdgcn_readlane(__float_as_uint(v), i));
}
// order-preserving float<->uint mapping for atomicMax on mixed-sign floats
__device__ __forceinline__ unsigned enc_f(float f) {
    unsigned u = __float_as_uint(f);
    return (int)u < 0 ? ~u : (u | 0x80000000u);
}
__device__ __forceinline__ float dec_f(unsigned e) {
    return __uint_as_float((int)e < 0 ? (e & 0x7FFFFFFFu) : ~e);
}

// ---------------------------------------------------------------------------
// GEMM body: h(fp16, split planes hA=dims0-31 / hB=dims32-63) = x@W,
// s_src/s_dst (f32). 64x64 tile, BK=32, 4x4/thread. Block s_src max goes to
// bmax[blockIdx] (layer 1, reduced later) or atomicMax (layer 2).
// ---------------------------------------------------------------------------
template <int K>
__device__ __forceinline__ void gemm_body(
    const float* __restrict__ x, const float* __restrict__ W,
    const float* __restrict__ a_src, const float* __restrict__ a_dst,
    __half* __restrict__ hA, __half* __restrict__ hB,
    float* __restrict__ s_src, float* __restrict__ s_dst,
    float* __restrict__ bmax, unsigned* __restrict__ gmax_enc, int n)
{
    constexpr int BK = 32;
    __shared__ float Wl[BK][64];
    __shared__ float xt[BK][68];
    __shared__ float asl[64], adl[64];
    __shared__ float wm[4];

    int tid = threadIdx.x;
    if (tid < 64) { asl[tid] = a_src[tid]; adl[tid] = a_dst[tid]; }
    int tx = tid & 15, ty = tid >> 4;
    int row0 = blockIdx.x * 64;

    float acc[4][4] = {};

    for (int k0 = 0; k0 < K; k0 += BK) {
        __syncthreads();
        {
            const float4* Wg = (const float4*)&W[(size_t)k0 * 64];
            float4* Ws = (float4*)&Wl[0][0];
            Ws[tid]       = Wg[tid];
            Ws[tid + 256] = Wg[tid + 256];
        }
        #pragma unroll
        for (int it = 0; it < 2; ++it) {
            int idx = tid + it * 256;
            int r = idx >> 3, kq = idx & 7;
            int grow = row0 + r;
            float4 v = (grow < n) ? *(const float4*)&x[(size_t)grow * K + k0 + kq * 4]
                                  : make_float4(0.f, 0.f, 0.f, 0.f);
            xt[kq * 4 + 0][r] = v.x;
            xt[kq * 4 + 1][r] = v.y;
            xt[kq * 4 + 2][r] = v.z;
            xt[kq * 4 + 3][r] = v.w;
        }
        __syncthreads();

        #pragma unroll
        for (int kk = 0; kk < BK; ++kk) {
            float4 wv = *(const float4*)&Wl[kk][tx * 4];
            float4 xv = *(const float4*)&xt[kk][ty * 4];
            acc[0][0] += xv.x * wv.x; acc[0][1] += xv.x * wv.y; acc[0][2] += xv.x * wv.z; acc[0][3] += xv.x * wv.w;
            acc[1][0] += xv.y * wv.x; acc[1][1] += xv.y * wv.y; acc[1][2] += xv.y * wv.z; acc[1][3] += xv.y * wv.w;
            acc[2][0] += xv.z * wv.x; acc[2][1] += xv.z * wv.y; acc[2][2] += xv.z * wv.z; acc[2][3] += xv.z * wv.w;
            acc[3][0] += xv.w * wv.x; acc[3][1] += xv.w * wv.y; acc[3][2] += xv.w * wv.z; acc[3][3] += xv.w * wv.w;
        }
    }

    float wmax = -INFINITY;
    #pragma unroll
    for (int i = 0; i < 4; ++i) {
        int grow = row0 + ty * 4 + i;
        if (grow < n) {
            __half2 p0 = __floats2half2_rn(acc[i][0], acc[i][1]);
            __half2 p1 = __floats2half2_rn(acc[i][2], acc[i][3]);
            uint2 pk = make_uint2(*(unsigned*)&p0, *(unsigned*)&p1);
            if (tx < 8)
                *(uint2*)&hA[(size_t)grow * 32 + tx * 4] = pk;
            else
                *(uint2*)&hB[(size_t)grow * 32 + (tx - 8) * 4] = pk;
        }
        float s1 = acc[i][0] * asl[tx*4+0] + acc[i][1] * asl[tx*4+1]
                 + acc[i][2] * asl[tx*4+2] + acc[i][3] * asl[tx*4+3];
        float s2 = acc[i][0] * adl[tx*4+0] + acc[i][1] * adl[tx*4+1]
                 + acc[i][2] * adl[tx*4+2] + acc[i][3] * adl[tx*4+3];
        #pragma unroll
        for (int m = 1; m < 16; m <<= 1) {
            s1 += __shfl_xor(s1, m, 64);
            s2 += __shfl_xor(s2, m, 64);
        }
        if (grow < n) wmax = fmaxf(wmax, s1);
        if (tx == 0 && grow < n) { s_src[grow] = s1; s_dst[grow] = s2; }
    }
    wmax = fmaxf(wmax, __shfl_xor(wmax, 16, 64));
    wmax = fmaxf(wmax, __shfl_xor(wmax, 32, 64));
    if ((tid & 63) == 0) wm[tid >> 6] = wmax;
    __syncthreads();
    if (tid == 0) {
        float bm = fmaxf(fmaxf(wm[0], wm[1]), fmaxf(wm[2], wm[3]));
        if (bmax) bmax[blockIdx.x] = bm;           // layer 1: reduced in P2
        else      atomicMax(gmax_enc, enc_f(bm));  // layer 2: gmaxu[1] zeroed in P2
    }
}

// K1: fused gemm1 (blocks 0..781) + CSR P1 histogram (blocks 782..981).
// Independent work -> free overlap, one less launch.
template <int K>
__global__ __launch_bounds__(256) void fused_gemm_p1(
    const float* __restrict__ x, const float* __restrict__ W,
    const float* __restrict__ a_src, const float* __restrict__ a_dst,
    __half* __restrict__ hA, __half* __restrict__ hB,
    float* __restrict__ s_src, float* __restrict__ s_dst,
    float* __restrict__ bmax,
    const int* __restrict__ dst_, int* __restrict__ cnt, int n)
{
    if (blockIdx.x >= GEMM_BLOCKS) {
        __shared__ int bins[NBKT];
        int tid = threadIdx.x, b = blockIdx.x - GEMM_BLOCKS;
        if (tid < NBKT) bins[tid] = 0;
        __syncthreads();
        int e0 = b * CHUNK;
        for (int e = e0 + tid; e < e0 + CHUNK; e += 256)
            atomicAdd(&bins[dst_[e] >> 8], 1);
        __syncthreads();
        if (tid < NBKT) cnt[b * NBKT + tid] = bins[tid];
        return;
    }
    gemm_body<K>(x, W, a_src, a_dst, hA, hB, s_src, s_dst, bmax, nullptr, n);
}

template <int K>
__global__ __launch_bounds__(256) void gat_gemm_kernel(
    const float* __restrict__ x, const float* __restrict__ W,
    const float* __restrict__ a_src, const float* __restrict__ a_dst,
    __half* __restrict__ hA, __half* __restrict__ hB,
    float* __restrict__ s_src, float* __restrict__ s_dst,
    unsigned* __restrict__ gmax_enc, int n)
{
    gemm_body<K>(x, W, a_src, a_dst, hA, hB, s_src, s_dst, nullptr, gmax_enc, n);
}

// ---------------------------------------------------------------------------
// CSR build P2-P4 (zero global atomics).
// P2: column scan of cnt + bucket totals; block 0 also reduces bmax -> gmaxu[0]
// and zeroes gmaxu[1].
// ---------------------------------------------------------------------------
__global__ __launch_bounds__(256) void p2_scan(
    int* __restrict__ cnt, int* __restrict__ btot,
    const float* __restrict__ bmax, unsigned* __restrict__ gmaxu)
{
    __shared__ int tmp[256];
    __shared__ float fm[4];
    int j = blockIdx.x, tid = threadIdx.x;
    int v = (tid < EBLK) ? cnt[tid * NBKT + j] : 0;
    tmp[tid] = v; __syncthreads();
    for (int off = 1; off < 256; off <<= 1) {
        int a = (tid >= off) ? tmp[tid - off] : 0;
        __syncthreads();
        tmp[tid] += a;
        __syncthreads();
    }
    if (tid < EBLK) cnt[tid * NBKT + j] = tmp[tid] - v;   // exclusive
    if (tid == EBLK - 1) btot[j] = tmp[tid];              // bucket total

    if (j == 0) {
        float m = -INFINITY;
        for (int i = tid; i < GEMM_BLOCKS; i += 256) m = fmaxf(m, bmax[i]);
        #pragma unroll
        for (int off = 32; off; off >>= 1) m = fmaxf(m, __shfl_xor(m, off, 64));
        if ((tid & 63) == 0) fm[tid >> 6] = m;
        __syncthreads();
        if (tid == 0) {
            gmaxu[0] = enc_f(fmaxf(fmaxf(fm[0], fm[1]), fmaxf(fm[2], fm[3])));
            gmaxu[1] = 0;
        }
    }
}

// P3: scatter edges into contiguous bucket regions; LDS cursors only.
__global__ __launch_bounds__(256) void p3_bucket(
    const int* __restrict__ src, const int* __restrict__ dst,
    const int* __restrict__ cnt, const int* __restrict__ btot,
    unsigned* __restrict__ bkted)
{
    __shared__ int tmp[256];
    __shared__ int boffL[NBKT];
    int b = blockIdx.x, tid = threadIdx.x;
    int v = (tid < NBKT) ? btot[tid] : 0;
    tmp[tid] = v; __syncthreads();
    for (int off = 1; off < 256; off <<= 1) {
        int a = (tid >= off) ? tmp[tid - off] : 0;
        __syncthreads();
        tmp[tid] += a;
        __syncthreads();
    }
    if (tid < NBKT) boffL[tid] = (tmp[tid] - v) + cnt[b * NBKT + tid];
    __syncthreads();
    int e0 = b * CHUNK;
    for (int e = e0 + tid; e < e0 + CHUNK; e += 256) {
        int d = dst[e], s = src[e];
        int pos = atomicAdd(&boffL[d >> 8], 1);
        bkted[pos] = ((unsigned)(d & 255) << 16) | (unsigned)s;
    }
}

// P4: one block per bucket; per-node count/scan/scatter in LDS.
__global__ __launch_bounds__(256) void p4_csr(
    const unsigned* __restrict__ bkted, const int* __restrict__ btot,
    int* __restrict__ row_off, int* __restrict__ csr_src)
{
    __shared__ int tmp[256];
    __shared__ int cur[256];
    __shared__ int s_beg, s_end;
    int j = blockIdx.x, tid = threadIdx.x;
    int v = (tid < NBKT) ? btot[tid] : 0;
    tmp[tid] = v; __syncthreads();
    for (int off = 1; off < 256; off <<= 1) {
        int a = (tid >= off) ? tmp[tid - off] : 0;
        __syncthreads();
        tmp[tid] += a;
        __syncthreads();
    }
    if (tid == j) { s_beg = tmp[tid] - v; s_end = tmp[tid]; }
    cur[tid] = 0;
    __syncthreads();
    int beg = s_beg, end = s_end;

    for (int e = beg + tid; e < end; e += 256)
        atomicAdd(&cur[bkted[e] >> 16], 1);
    __syncthreads();
    int c = cur[tid];
    tmp[tid] = c; __syncthreads();
    for (int off = 1; off < 256; off <<= 1) {
        int a = (tid >= off) ? tmp[tid - off] : 0;
        __syncthreads();
        tmp[tid] += a;
        __syncthreads();
    }
    int offx = tmp[tid] - c;
    int node = j * 256 + tid;
    if (node < N_NODES) row_off[node] = beg + offx;
    if (node == 0) row_off[N_NODES] = N_EDGES;
    __syncthreads();
    cur[tid] = offx;
    __syncthreads();
    for (int e = beg + tid; e < end; e += 256) {
        unsigned u = bkted[e];
        int pos = beg + atomicAdd(&cur[u >> 16], 1);
        csr_src[pos] = (int)(u & 0xFFFFu);
    }
}

// ---------------------------------------------------------------------------
// Plane-split fused per-node attention kernel. One wave per node; lanes =
// 2 edges x 32 dims; plane = 3.2 MB fp16 -> fits one XCD L2. Two dispatches
// per layer (temporal separation keeps the plane L2-resident). Streaming
// accesses (csr_src, out) use nontemporal hints to avoid evicting the plane.
// ---------------------------------------------------------------------------
template <bool RELU, int PLANE>
__global__ __launch_bounds__(256) void gat_node_kernel(
    const int* __restrict__ row_off, const int* __restrict__ csr_src,
    const float* __restrict__ s_src, const float* __restrict__ s_dst,
    const __half* __restrict__ hp, const float* __restrict__ b,
    const unsigned* __restrict__ gmax_enc, float* __restrict__ out, int n)
{
    int row = blockIdx.x * 4 + (threadIdx.x >> 6);
    int lane = threadIdx.x & 63;
    if (row >= n) return;
    int es = lane >> 5;            // edge slot (0/1)
    int d  = lane & 31;            // dim within plane

    int beg = row_off[row], end = row_off[row + 1];
    int deg = end - beg;
    float sd = s_dst[row];
    float m = leaky(dec_f(*gmax_enc) + sd);     // uniform upper bound, cancels
    float s_self = s_src[row];
    float hself = __half2float(hp[(size_t)row * 32 + d]);
    float wself = __expf(leaky(s_self + sd) - m);

    // pass A: one edge per lane (up to 64)
    int   mysrc   = row;                        // filler: hot self row, w=0
    float mylogit = -INFINITY;
    if (lane < deg) {
        mysrc = __builtin_nontemporal_load(&csr_src[beg + lane]);
        mylogit = leaky(s_src[mysrc] + sd);
    }
    float w64 = __expf(mylogit - m);
    float den = w64;
    #pragma unroll
    for (int off = 32; off; off >>= 1)
        den += __shfl_xor(den, off, 64);
    den += wself;

    float acc = (es == 0) ? wself * hself : 0.f;

    // pass B: pairs of edges per instruction (16 loads cover 32 edges)
    int d0 = deg < 64 ? deg : 64;
    for (int base = 0; base < d0; base += 32) {
        float hv[16];
        #pragma unroll
        for (int j = 0; j < 16; ++j) {
            int s0 = __builtin_amdgcn_readlane(mysrc, base + 2 * j);
            int s1 = __builtin_amdgcn_readlane(mysrc, base + 2 * j + 1);
            int s = es ? s1 : s0;
            hv[j] = __half2float(hp[(size_t)s * 32 + d]);
        }
        #pragma unroll
        for (int j = 0; j < 16; ++j) {
            float w0 = readlane_f(w64, base + 2 * j);
            float w1 = readlane_f(w64, base + 2 * j + 1);
            acc += (es ? w1 : w0) * hv[j];
        }
    }
    for (int e = beg + 64; e < end; ++e) {      // rare tail: deg > 64
        int s = __builtin_nontemporal_load(&csr_src[e]);
        float w = __expf(leaky(s_src[s] + sd) - m);
        den += w;
        if (es == 0) acc += w * __half2float(hp[(size_t)s * 32 + d]);
    }

    acc += __shfl_xor(acc, 32, 64);             // sum the two edge slots

    if (es == 0) {
        float v = acc / den + b[PLANE * 32 + d];
        if (RELU) v = fmaxf(v, 0.f);
        __builtin_nontemporal_store(v, &out[(size_t)row * 64 + PLANE * 32 + d]);
    }
}

// ---------------------------------------------------------------------------
extern "C" void kernel_launch(void* const* d_in, const int* in_sizes, int n_in,
                              void* d_out, int out_size, void* d_ws, size_t ws_size,
                              hipStream_t stream) {
    const float* x   = (const float*)d_in[0];
    const int*   ei  = (const int*)d_in[1];
    const float* W1  = (const float*)d_in[2];
    const float* a1s = (const float*)d_in[3];
    const float* a1d = (const float*)d_in[4];
    const float* b1  = (const float*)d_in[5];
    const float* W2  = (const float*)d_in[6];
    const float* a2s = (const float*)d_in[7];
    const float* a2d = (const float*)d_in[8];
    const float* b2  = (const float*)d_in[9];
    float* out = (float*)d_out;

    const int* src = ei;
    const int* dst = ei + N_EDGES;

    char* p = (char*)d_ws;
    __half* hA  = (__half*)p;           p += (size_t)N_NODES * 32 * 2;  // 3.2 MB
    __half* hB  = (__half*)p;           p += (size_t)N_NODES * 32 * 2;  // 3.2 MB
    float* ssrc = (float*)p;            p += (size_t)N_NODES * 4;
    float* sdst = (float*)p;            p += (size_t)N_NODES * 4;
    int* row_off = (int*)p;             p += (size_t)(N_NODES + 1) * 4;
    unsigned* gmaxu = (unsigned*)p;     p += 4 * 4;
    float* bmax = (float*)p;            p += 1024 * 4;
    int* csr_src = (int*)p;             p += (size_t)N_EDGES * 4;       // 3.2 MB
    int* cnt     = (int*)p;             p += (size_t)EBLK * NBKT * 4;
    int* btot    = (int*)p;             p += (size_t)NBKT * 4;
    unsigned* bkted = (unsigned*)p;     p += (size_t)N_EDGES * 4;       // 3.2 MB

    dim3 blk(256);
    int node_blocks = (N_NODES + 3) / 4;

    // ---- K1: gemm1 (x@W1 -> hA,hB, scores, bmax) || CSR P1 histogram ----
    fused_gemm_p1<128><<<GEMM_BLOCKS + EBLK, blk, 0, stream>>>(
        x, W1, a1s, a1d, hA, hB, ssrc, sdst, bmax, dst, cnt, N_NODES);
    // ---- CSR P2-P4 (+ gmax1 reduce, gmax2 zero) ----
    p2_scan<<<NBKT, blk, 0, stream>>>(cnt, btot, bmax, gmaxu);
    p3_bucket<<<EBLK, blk, 0, stream>>>(src, dst, cnt, btot, bkted);
    p4_csr<<<NBKT, blk, 0, stream>>>(bkted, btot, row_off, csr_src);

    // ---- layer 1 aggregation: plane A, then plane B (L2-resident each) ----
    gat_node_kernel<true, 0><<<node_blocks, blk, 0, stream>>>(
        row_off, csr_src, ssrc, sdst, hA, b1, gmaxu + 0, out, N_NODES);
    gat_node_kernel<true, 1><<<node_blocks, blk, 0, stream>>>(
        row_off, csr_src, ssrc, sdst, hB, b1, gmaxu + 0, out, N_NODES);

    // ---- layer 2 ----
    gat_gemm_kernel<64><<<GEMM_BLOCKS, blk, 0, stream>>>(
        out, W2, a2s, a2d, hA, hB, ssrc, sdst, gmaxu + 1, N_NODES);
    gat_node_kernel<false, 0><<<node_blocks, blk, 0, stream>>>(
        row_off, csr_src, ssrc, sdst, hA, b2, gmaxu + 1, out, N_NODES);
    gat_node_kernel<false, 1><<<node_blocks, blk, 0, stream>>>(
        row_off, csr_src, ssrc, sdst, hB, b2, gmaxu + 1, out, N_NODES);
}

// Round 12
// 147.476 us; speedup vs baseline: 1.3811x; 1.3811x over previous
//
#include <hip/hip_runtime.h>
#include <hip/hip_fp16.h>

#define N_NODES 50000
#define N_EDGES 800000
#define NEG_SLOPE 0.2f
#define NBKT 196            // ceil(50000/256) buckets of 256 nodes
#define EBLK 200            // edge blocks
#define CHUNK 4000          // edges per block (EBLK*CHUNK == N_EDGES)

__device__ __forceinline__ float leaky(float x) { return x >= 0.f ? x : NEG_SLOPE * x; }
// order-preserving float<->uint mapping for atomicMax on mixed-sign floats
__device__ __forceinline__ unsigned enc_f(float f) {
    unsigned u = __float_as_uint(f);
    return (int)u < 0 ? ~u : (u | 0x80000000u);
}
__device__ __forceinline__ float dec_f(unsigned e) {
    return __uint_as_float((int)e < 0 ? (e & 0x7FFFFFFFu) : ~e);
}

// ---------------------------------------------------------------------------
// Register-tiled GEMM + attention scores: h(fp16) = x@W, s_src/s_dst (f32),
// gmax accumulated via one encoded atomicMax per block. (R10-identical)
// ---------------------------------------------------------------------------
template <int K>
__global__ __launch_bounds__(256) void gat_gemm_kernel(
    const float* __restrict__ x, const float* __restrict__ W,
    const float* __restrict__ a_src, const float* __restrict__ a_dst,
    __half* __restrict__ h, float* __restrict__ s_src, float* __restrict__ s_dst,
    unsigned* __restrict__ gmax_enc, int n)
{
    constexpr int BK = 32;
    __shared__ float Wl[BK][64];
    __shared__ float xt[BK][68];
    __shared__ float asl[64], adl[64];
    __shared__ float wm[4];

    int tid = threadIdx.x;
    if (tid < 64) { asl[tid] = a_src[tid]; adl[tid] = a_dst[tid]; }
    int tx = tid & 15, ty = tid >> 4;
    int row0 = blockIdx.x * 64;

    float acc[4][4] = {};

    for (int k0 = 0; k0 < K; k0 += BK) {
        __syncthreads();
        {
            const float4* Wg = (const float4*)&W[(size_t)k0 * 64];
            float4* Ws = (float4*)&Wl[0][0];
            Ws[tid]       = Wg[tid];
            Ws[tid + 256] = Wg[tid + 256];
        }
        #pragma unroll
        for (int it = 0; it < 2; ++it) {
            int idx = tid + it * 256;
            int r = idx >> 3, kq = idx & 7;
            int grow = row0 + r;
            float4 v = (grow < n) ? *(const float4*)&x[(size_t)grow * K + k0 + kq * 4]
                                  : make_float4(0.f, 0.f, 0.f, 0.f);
            xt[kq * 4 + 0][r] = v.x;
            xt[kq * 4 + 1][r] = v.y;
            xt[kq * 4 + 2][r] = v.z;
            xt[kq * 4 + 3][r] = v.w;
        }
        __syncthreads();

        #pragma unroll
        for (int kk = 0; kk < BK; ++kk) {
            float4 wv = *(const float4*)&Wl[kk][tx * 4];
            float4 xv = *(const float4*)&xt[kk][ty * 4];
            acc[0][0] += xv.x * wv.x; acc[0][1] += xv.x * wv.y; acc[0][2] += xv.x * wv.z; acc[0][3] += xv.x * wv.w;
            acc[1][0] += xv.y * wv.x; acc[1][1] += xv.y * wv.y; acc[1][2] += xv.y * wv.z; acc[1][3] += xv.y * wv.w;
            acc[2][0] += xv.z * wv.x; acc[2][1] += xv.z * wv.y; acc[2][2] += xv.z * wv.z; acc[2][3] += xv.z * wv.w;
            acc[3][0] += xv.w * wv.x; acc[3][1] += xv.w * wv.y; acc[3][2] += xv.w * wv.z; acc[3][3] += xv.w * wv.w;
        }
    }

    float wmax = -INFINITY;
    #pragma unroll
    for (int i = 0; i < 4; ++i) {
        int grow = row0 + ty * 4 + i;
        if (grow < n) {
            __half2 p0 = __floats2half2_rn(acc[i][0], acc[i][1]);
            __half2 p1 = __floats2half2_rn(acc[i][2], acc[i][3]);
            uint2 pk = make_uint2(*(unsigned*)&p0, *(unsigned*)&p1);
            *(uint2*)&h[(size_t)grow * 64 + tx * 4] = pk;
        }
        float s1 = acc[i][0] * asl[tx*4+0] + acc[i][1] * asl[tx*4+1]
                 + acc[i][2] * asl[tx*4+2] + acc[i][3] * asl[tx*4+3];
        float s2 = acc[i][0] * adl[tx*4+0] + acc[i][1] * adl[tx*4+1]
                 + acc[i][2] * adl[tx*4+2] + acc[i][3] * adl[tx*4+3];
        #pragma unroll
        for (int m = 1; m < 16; m <<= 1) {
            s1 += __shfl_xor(s1, m, 64);
            s2 += __shfl_xor(s2, m, 64);
        }
        if (grow < n) wmax = fmaxf(wmax, s1);
        if (tx == 0 && grow < n) { s_src[grow] = s1; s_dst[grow] = s2; }
    }
    wmax = fmaxf(wmax, __shfl_xor(wmax, 16, 64));
    wmax = fmaxf(wmax, __shfl_xor(wmax, 32, 64));
    if ((tid & 63) == 0) wm[tid >> 6] = wmax;
    __syncthreads();
    if (tid == 0) {
        float bm = fmaxf(fmaxf(wm[0], wm[1]), fmaxf(wm[2], wm[3]));
        atomicMax(gmax_enc, enc_f(bm));
    }
}

// ---------------------------------------------------------------------------
// CSR build, zero global atomics (R10-identical).
// ---------------------------------------------------------------------------
__global__ __launch_bounds__(256) void p1_count(
    const int* __restrict__ dst, int* __restrict__ cnt, unsigned* __restrict__ gmaxu)
{
    __shared__ int bins[NBKT];
    int tid = threadIdx.x, b = blockIdx.x;
    if (tid < NBKT) bins[tid] = 0;
    if (b == 0 && tid >= 254) gmaxu[tid - 254] = 0;
    __syncthreads();
    int e0 = b * CHUNK;
    for (int e = e0 + tid; e < e0 + CHUNK; e += 256)
        atomicAdd(&bins[dst[e] >> 8], 1);
    __syncthreads();
    if (tid < NBKT) cnt[b * NBKT + tid] = bins[tid];
}

__global__ __launch_bounds__(256) void p2_scan(
    int* __restrict__ cnt, int* __restrict__ btot)
{
    __shared__ int tmp[256];
    int j = blockIdx.x, tid = threadIdx.x;
    int v = (tid < EBLK) ? cnt[tid * NBKT + j] : 0;
    tmp[tid] = v; __syncthreads();
    for (int off = 1; off < 256; off <<= 1) {
        int a = (tid >= off) ? tmp[tid - off] : 0;
        __syncthreads();
        tmp[tid] += a;
        __syncthreads();
    }
    if (tid < EBLK) cnt[tid * NBKT + j] = tmp[tid] - v;   // exclusive
    if (tid == EBLK - 1) btot[j] = tmp[tid];              // bucket total
}

__global__ __launch_bounds__(256) void p3_bucket(
    const int* __restrict__ src, const int* __restrict__ dst,
    const int* __restrict__ cnt, const int* __restrict__ btot,
    unsigned* __restrict__ bkted)
{
    __shared__ int tmp[256];
    __shared__ int boffL[NBKT];
    int b = blockIdx.x, tid = threadIdx.x;
    int v = (tid < NBKT) ? btot[tid] : 0;
    tmp[tid] = v; __syncthreads();
    for (int off = 1; off < 256; off <<= 1) {
        int a = (tid >= off) ? tmp[tid - off] : 0;
        __syncthreads();
        tmp[tid] += a;
        __syncthreads();
    }
    if (tid < NBKT) boffL[tid] = (tmp[tid] - v) + cnt[b * NBKT + tid];
    __syncthreads();
    int e0 = b * CHUNK;
    for (int e = e0 + tid; e < e0 + CHUNK; e += 256) {
        int d = dst[e], s = src[e];
        int pos = atomicAdd(&boffL[d >> 8], 1);
        bkted[pos] = ((unsigned)(d & 255) << 16) | (unsigned)s;
    }
}

__global__ __launch_bounds__(256) void p4_csr(
    const unsigned* __restrict__ bkted, const int* __restrict__ btot,
    int* __restrict__ row_off, int* __restrict__ csr_src)
{
    __shared__ int tmp[256];
    __shared__ int cur[256];
    __shared__ int s_beg, s_end;
    int j = blockIdx.x, tid = threadIdx.x;
    int v = (tid < NBKT) ? btot[tid] : 0;
    tmp[tid] = v; __syncthreads();
    for (int off = 1; off < 256; off <<= 1) {
        int a = (tid >= off) ? tmp[tid - off] : 0;
        __syncthreads();
        tmp[tid] += a;
        __syncthreads();
    }
    if (tid == j) { s_beg = tmp[tid] - v; s_end = tmp[tid]; }
    cur[tid] = 0;
    __syncthreads();
    int beg = s_beg, end = s_end;

    for (int e = beg + tid; e < end; e += 256)
        atomicAdd(&cur[bkted[e] >> 16], 1);
    __syncthreads();
    int c = cur[tid];
    tmp[tid] = c; __syncthreads();
    for (int off = 1; off < 256; off <<= 1) {
        int a = (tid >= off) ? tmp[tid - off] : 0;
        __syncthreads();
        tmp[tid] += a;
        __syncthreads();
    }
    int offx = tmp[tid] - c;
    int node = j * 256 + tid;
    if (node < N_NODES) row_off[node] = beg + offx;
    if (node == 0) row_off[N_NODES] = N_EDGES;
    __syncthreads();
    cur[tid] = offx;
    __syncthreads();
    for (int e = beg + tid; e < end; e += 256) {
        unsigned u = bkted[e];
        int pos = beg + atomicAdd(&cur[u >> 16], 1);
        csr_src[pos] = (int)(u & 0xFFFFu);
    }
}

// ---------------------------------------------------------------------------
// Fused per-node attention kernel. One wave per node.
// Pass B packs 4 EDGES PER GATHER INSTRUCTION: lane = (q=edge slot 0-3,
// t=dim quarter 0-15); each lane loads uint2 = 4 fp16 dims of edge q's row.
// 200k load instrs/dispatch (vs 800k) -> attacks the per-CU instruction wall.
// ---------------------------------------------------------------------------
template <bool RELU>
__global__ __launch_bounds__(256) void gat_node_kernel(
    const int* __restrict__ row_off, const int* __restrict__ csr_src,
    const float* __restrict__ s_src, const float* __restrict__ s_dst,
    const __half* __restrict__ h, const float* __restrict__ b,
    const unsigned* __restrict__ gmax_enc, float* __restrict__ out, int n)
{
    int row = blockIdx.x * 4 + (threadIdx.x >> 6);
    int lane = threadIdx.x & 63;
    if (row >= n) return;
    int q = lane >> 4;             // edge slot within a gather instruction
    int t = lane & 15;             // dim quarter (dims 4t..4t+3)

    int beg = row_off[row], end = row_off[row + 1];
    int deg = end - beg;
    float sd = s_dst[row];
    float m = leaky(dec_f(*gmax_enc) + sd);     // uniform upper bound, cancels
    float wself = __expf(leaky(s_src[row] + sd) - m);

    // pass A: one edge per lane
    int   mysrc   = row;                        // filler: hot self row, w=0
    float mylogit = -INFINITY;
    if (lane < deg) {
        mysrc = csr_src[beg + lane];
        mylogit = leaky(s_src[mysrc] + sd);
    }
    float w64 = __expf(mylogit - m);
    float den = w64;
    #pragma unroll
    for (int off = 32; off; off >>= 1)
        den += __shfl_xor(den, off, 64);
    den += wself;

    float4 acc = make_float4(0.f, 0.f, 0.f, 0.f);

    if (deg <= 64) {
        // pass B: 4 edges per load instruction; batches of 32 edges (8 loads)
        for (int base = 0; base < deg; base += 32) {
            uint2 hv[8]; float wj[8];
            #pragma unroll
            for (int j = 0; j < 8; ++j) {
                int idx = base + 4 * j + q;
                int   s = __shfl(mysrc, idx, 64);
                wj[j]   = __shfl(w64,   idx, 64);
                hv[j] = *(const uint2*)&h[(size_t)s * 64 + 4 * t];
            }
            #pragma unroll
            for (int j = 0; j < 8; ++j) {
                float2 lo = __half22float2(*(__half2*)&hv[j].x);
                float2 hi = __half22float2(*(__half2*)&hv[j].y);
                acc.x += wj[j] * lo.x; acc.y += wj[j] * lo.y;
                acc.z += wj[j] * hi.x; acc.w += wj[j] * hi.y;
            }
        }
    } else {
        // generic path: deg > 64 (rare). 4-edges-per-instr over full range.
        int nb = (deg + 31) & ~31;
        for (int base = 0; base < nb; base += 32) {
            uint2 hv[8]; float wj[8];
            #pragma unroll
            for (int j = 0; j < 8; ++j) {
                int idx = base + 4 * j + q;
                int e = beg + idx;
                int s = (idx < deg) ? csr_src[e] : row;
                float w = (idx < deg) ? __expf(leaky(s_src[s] + sd) - m) : 0.f;
                if (idx >= 64 && idx < deg) den += w / 64.f;  // placeholder, fixed below
                wj[j] = w;
                hv[j] = *(const uint2*)&h[(size_t)s * 64 + 4 * t];
            }
            #pragma unroll
            for (int j = 0; j < 8; ++j) {
                float2 lo = __half22float2(*(__half2*)&hv[j].x);
                float2 hi = __half22float2(*(__half2*)&hv[j].y);
                acc.x += wj[j] * lo.x; acc.y += wj[j] * lo.y;
                acc.z += wj[j] * hi.x; acc.w += wj[j] * hi.y;
            }
        }
        // recompute den exactly (pass A covered only first 64 edges)
        den = wself;
        for (int e = beg + lane; e < end; e += 64)
            den += __expf(leaky(s_src[csr_src[e]] + sd) - m);
        #pragma unroll
        for (int off = 32; off; off >>= 1)
            den += __shfl_xor(den, off, 64);
        // note: acc already holds per-(q,t) partial sums; den now exact.
    }

    // sum the 4 edge slots (lanes with equal t share dims)
    acc.x += __shfl_xor(acc.x, 16, 64); acc.x += __shfl_xor(acc.x, 32, 64);
    acc.y += __shfl_xor(acc.y, 16, 64); acc.y += __shfl_xor(acc.y, 32, 64);
    acc.z += __shfl_xor(acc.z, 16, 64); acc.z += __shfl_xor(acc.z, 32, 64);
    acc.w += __shfl_xor(acc.w, 16, 64); acc.w += __shfl_xor(acc.w, 32, 64);

    if (q == 0) {
        // add self contribution and finalize (lane t covers dims 4t..4t+3)
        uint2 hs = *(const uint2*)&h[(size_t)row * 64 + 4 * t];
        float2 lo = __half22float2(*(__half2*)&hs.x);
        float2 hi = __half22float2(*(__half2*)&hs.y);
        float4 v;
        v.x = (acc.x + wself * lo.x) / den + b[4*t+0];
        v.y = (acc.y + wself * lo.y) / den + b[4*t+1];
        v.z = (acc.z + wself * hi.x) / den + b[4*t+2];
        v.w = (acc.w + wself * hi.y) / den + b[4*t+3];
        if (RELU) {
            v.x = fmaxf(v.x, 0.f); v.y = fmaxf(v.y, 0.f);
            v.z = fmaxf(v.z, 0.f); v.w = fmaxf(v.w, 0.f);
        }
        *(float4*)&out[(size_t)row * 64 + 4 * t] = v;
    }
}

// ---------------------------------------------------------------------------
extern "C" void kernel_launch(void* const* d_in, const int* in_sizes, int n_in,
                              void* d_out, int out_size, void* d_ws, size_t ws_size,
                              hipStream_t stream) {
    const float* x   = (const float*)d_in[0];
    const int*   ei  = (const int*)d_in[1];
    const float* W1  = (const float*)d_in[2];
    const float* a1s = (const float*)d_in[3];
    const float* a1d = (const float*)d_in[4];
    const float* b1  = (const float*)d_in[5];
    const float* W2  = (const float*)d_in[6];
    const float* a2s = (const float*)d_in[7];
    const float* a2d = (const float*)d_in[8];
    const float* b2  = (const float*)d_in[9];
    float* out = (float*)d_out;

    const int* src = ei;
    const int* dst = ei + N_EDGES;

    char* p = (char*)d_ws;
    __half* h   = (__half*)p;           p += (size_t)N_NODES * 64 * 2;
    float* ssrc = (float*)p;            p += (size_t)N_NODES * 4;
    float* sdst = (float*)p;            p += (size_t)N_NODES * 4;
    int* row_off = (int*)p;             p += (size_t)(N_NODES + 1) * 4;
    unsigned* gmaxu = (unsigned*)p;     p += 4 * 4;
    int* csr_src = (int*)p;             p += (size_t)N_EDGES * 4;
    int* cnt     = (int*)p;             p += (size_t)EBLK * NBKT * 4;
    int* btot    = (int*)p;             p += (size_t)NBKT * 4;

    unsigned* bkted = (unsigned*)h;  // h dead until gemm1; bkted = 3.2 MB

    dim3 blk(256);
    int gemm_blocks = (N_NODES + 63) / 64;
    int node_blocks = (N_NODES + 3) / 4;

    // ---- CSR build: zero global atomics ----
    p1_count<<<EBLK, blk, 0, stream>>>(dst, cnt, gmaxu);
    p2_scan<<<NBKT, blk, 0, stream>>>(cnt, btot);
    p3_bucket<<<EBLK, blk, 0, stream>>>(src, dst, cnt, btot, bkted);
    p4_csr<<<NBKT, blk, 0, stream>>>(bkted, btot, row_off, csr_src);

    // ---- layer 1 ----
    gat_gemm_kernel<128><<<gemm_blocks, blk, 0, stream>>>(x, W1, a1s, a1d, h, ssrc, sdst, gmaxu + 0, N_NODES);
    gat_node_kernel<true><<<node_blocks, blk, 0, stream>>>(row_off, csr_src, ssrc, sdst, h, b1, gmaxu + 0, out, N_NODES);

    // ---- layer 2 ----
    gat_gemm_kernel<64><<<gemm_blocks, blk, 0, stream>>>(out, W2, a2s, a2d, h, ssrc, sdst, gmaxu + 1, N_NODES);
    gat_node_kernel<false><<<node_blocks, blk, 0, stream>>>(row_off, csr_src, ssrc, sdst, h, b2, gmaxu + 1, out, N_NODES);
}